// Round 1
// baseline (531.075 us; speedup 1.0000x reference)
//
#include <hip/hip_runtime.h>
#include <math.h>

// Problem constants
#define NPOS    65536       // BS*H*W = 16*64*64
#define KSLOT   512
#define DIM     64
#define PITCH   513         // LDS row pitch (odd -> conflict-free strided access)

// Output layout (floats): z_q [16,64,64,64] | hard_indices [16,64,64] | KL | commit
#define IDX_OFF 4194304
#define KL_OFF  4259840
#define CM_OFF  4259841

#define LOG_K   6.238324625039508f   // ln(512)

__device__ __forceinline__ float wave_sum(float v){
#pragma unroll
  for (int m = 1; m < 64; m <<= 1) v += __shfl_xor(v, m, 64);
  return v;
}
__device__ __forceinline__ float wave_max(float v){
#pragma unroll
  for (int m = 1; m < 64; m <<= 1) v = fmaxf(v, __shfl_xor(v, m, 64));
  return v;
}

struct SMem {
  float A[64 * PITCH];   // phase1: codebook transposed [c][k] ; phase2/3: soft weights [p][k]
  float Z[64 * 64];      // z tile transposed [c][p]
  float CC[512];         // ||c_k||^2
  float ZZ[64];          // ||z_p||^2
  float RED[32];         // per-wave KL / commit partials
};

__global__ __launch_bounds__(1024) void vq_fused(
    const float* __restrict__ ze, const float* __restrict__ cbk,
    const float* __restrict__ u, float* __restrict__ out)
{
  __shared__ SMem sm;
  const int tid  = threadIdx.x;
  const int lane = tid & 63;
  const int wv   = tid >> 6;
  const int blk  = blockIdx.x;      // 0..1023 ; tile = one (b,h) row, w = 0..63
  const int bb   = blk >> 6;        // batch
  const int hh   = blk & 63;        // h row
  const int n0   = blk << 6;        // first flat position of tile

  // ---- stage codebook transposed: sm.A[c*PITCH + k] = cbk[k*64 + c]
  {
    const int krow = tid >> 4;           // 0..63
    const int c0   = (tid & 15) << 2;    // 0,4,...,60
#pragma unroll
    for (int it = 0; it < 8; ++it){
      const int k = krow + (it << 6);
      const float4 v = *(const float4*)(cbk + k * 64 + c0);
      sm.A[(c0 + 0) * PITCH + k] = v.x;
      sm.A[(c0 + 1) * PITCH + k] = v.y;
      sm.A[(c0 + 2) * PITCH + k] = v.z;
      sm.A[(c0 + 3) * PITCH + k] = v.w;
    }
  }
  // ---- stage z tile: sm.Z[c*64 + w] = ze[bb][c][hh][w]  (coalesced rows)
  {
    const float* zb = ze + ((size_t)bb << 18) + (hh << 6);
#pragma unroll
    for (int it = 0; it < 4; ++it){
      const int idx = tid + (it << 10);
      const int c = idx >> 6, w = idx & 63;
      sm.Z[idx] = zb[(c << 12) + w];
    }
  }
  __syncthreads();

  // ---- norms
  if (tid < 512){
    float s = 0.f;
#pragma unroll 8
    for (int c = 0; c < 64; ++c){ const float v = sm.A[c * PITCH + tid]; s = fmaf(v, v, s); }
    sm.CC[tid] = s;
  } else if (tid < 576){
    const int p = tid - 512;
    float s = 0.f;
#pragma unroll 8
    for (int c = 0; c < 64; ++c){ const float v = sm.Z[(c << 6) + p]; s = fmaf(v, v, s); }
    sm.ZZ[p] = s;
  }
  __syncthreads();

  // ---- phase 1: dots. wave -> 4 positions (q0..q0+3), lane -> 8 slots (k = lane + 64j)
  const int q0 = wv << 2;
  float acc[4][8];
#pragma unroll
  for (int pp = 0; pp < 4; ++pp)
#pragma unroll
    for (int j = 0; j < 8; ++j) acc[pp][j] = 0.f;

#pragma unroll 4
  for (int c = 0; c < 64; ++c){
    float cv[8];
#pragma unroll
    for (int j = 0; j < 8; ++j) cv[j] = sm.A[c * PITCH + lane + (j << 6)];  // conflict-free
    float zv[4];
#pragma unroll
    for (int pp = 0; pp < 4; ++pp) zv[pp] = sm.Z[(c << 6) + q0 + pp];       // broadcast
#pragma unroll
    for (int pp = 0; pp < 4; ++pp)
#pragma unroll
      for (int j = 0; j < 8; ++j) acc[pp][j] = fmaf(zv[pp], cv[j], acc[pp][j]);
  }
  // logits = -(cc + zz - 2*dot)
  {
    float cc[8];
#pragma unroll
    for (int j = 0; j < 8; ++j) cc[j] = sm.CC[lane + (j << 6)];
#pragma unroll
    for (int pp = 0; pp < 4; ++pp){
      const float zz = sm.ZZ[q0 + pp];
#pragma unroll
      for (int j = 0; j < 8; ++j) acc[pp][j] = fmaf(2.f, acc[pp][j], -cc[j] - zz);
    }
  }
  __syncthreads();   // codebook LDS tile dead; sm.A becomes soft-weight storage

  // ---- phase 2: gumbel softmax + probs + KL/commit, per position
  float klacc = 0.f, cmacc = 0.f;
#pragma unroll 1
  for (int pp = 0; pp < 4; ++pp){
    const int q = q0 + pp;
    const int n = n0 + q;
    const float* urow = u + ((size_t)n << 9);
    float a[8], e[8];
    float amax = -3.4e38f; int kbest = 0;
#pragma unroll
    for (int j = 0; j < 8; ++j){
      const float uu = urow[lane + (j << 6)];                       // coalesced
      const float g  = -__logf(-__logf(uu + 1e-10f) + 1e-10f);      // gumbel
      const float aj = (acc[pp][j] + g) * 2.0f;                     // (logits+g)/T, T=0.5
      a[j] = aj;
      if (aj > amax){ amax = aj; kbest = lane + (j << 6); }         // keeps earliest j
    }
    // wave argmax: (max value, min index on ties) -- matches jnp.argmax first-max
#pragma unroll
    for (int m = 1; m < 64; m <<= 1){
      const float vo = __shfl_xor(amax, m, 64);
      const int   io = __shfl_xor(kbest, m, 64);
      if (vo > amax || (vo == amax && io < kbest)){ amax = vo; kbest = io; }
    }
    float s1 = 0.f;
#pragma unroll
    for (int j = 0; j < 8; ++j){ e[j] = __expf(a[j] - amax); s1 += e[j]; }
    s1 = wave_sum(s1);
    const float inv1 = 1.0f / s1;
#pragma unroll
    for (int j = 0; j < 8; ++j) sm.A[q * PITCH + lane + (j << 6)] = e[j] * inv1;
    if (lane == 0) out[IDX_OFF + n] = (float)kbest;

    // probs = softmax(logits) ; KL and commit partials
    float lmax = acc[pp][0];
#pragma unroll
    for (int j = 1; j < 8; ++j) lmax = fmaxf(lmax, acc[pp][j]);
    lmax = wave_max(lmax);
    float s2 = 0.f;
#pragma unroll
    for (int j = 0; j < 8; ++j){ e[j] = __expf(acc[pp][j] - lmax); s2 += e[j]; }
    s2 = wave_sum(s2);
    const float inv2 = 1.0f / s2;
#pragma unroll
    for (int j = 0; j < 8; ++j){
      const float p = e[j] * inv2;
      klacc += p * (__logf(p + 1e-9f) + LOG_K);
      cmacc -= p * acc[pp][j];                    // distances = -logits
    }
  }
  klacc = wave_sum(klacc);
  cmacc = wave_sum(cmacc);
  if (lane == 0){ sm.RED[wv] = klacc; sm.RED[wv + 16] = cmacc; }
  __syncthreads();   // also gates phase 3 on all soft-weight writes
  if (tid == 0){
    float tk = 0.f, tc = 0.f;
#pragma unroll
    for (int i = 0; i < 16; ++i){ tk += sm.RED[i]; tc += sm.RED[i + 16]; }
    atomicAdd(out + KL_OFF, tk * 0.0625f);   // mean over BS=16
    atomicAdd(out + CM_OFF, tc * 0.0625f);
  }

  // ---- phase 3: z_q[p][c] = sum_k soft[p][k] * cbk[k][c]
  {
    const int w  = tid & 63;            // position within tile
    const int c0 = (tid >> 6) << 2;     // wave-uniform channel group
    float o0 = 0.f, o1 = 0.f, o2 = 0.f, o3 = 0.f;
#pragma unroll 4
    for (int k = 0; k < 512; ++k){
      const float s = sm.A[w * PITCH + k];                 // conflict-free (odd pitch)
      const float4 cv = *(const float4*)(cbk + k * 64 + c0); // wave-uniform -> L1 broadcast
      o0 = fmaf(s, cv.x, o0);
      o1 = fmaf(s, cv.y, o1);
      o2 = fmaf(s, cv.z, o2);
      o3 = fmaf(s, cv.w, o3);
    }
    float* zq = out + ((size_t)bb << 18) + (hh << 6) + w;  // z_q[bb][c][hh][w]
    zq[(size_t)(c0 + 0) << 12] = o0;   // coalesced across lanes (w contiguous)
    zq[(size_t)(c0 + 1) << 12] = o1;
    zq[(size_t)(c0 + 2) << 12] = o2;
    zq[(size_t)(c0 + 3) << 12] = o3;
  }
}

extern "C" void kernel_launch(void* const* d_in, const int* in_sizes, int n_in,
                              void* d_out, int out_size, void* d_ws, size_t ws_size,
                              hipStream_t stream){
  const float* ze  = (const float*)d_in[0];
  const float* cbk = (const float*)d_in[1];
  const float* u   = (const float*)d_in[2];
  float* out = (float*)d_out;
  // zero the two scalar accumulators (d_out is re-poisoned before every launch)
  hipMemsetAsync(out + KL_OFF, 0, 2 * sizeof(float), stream);
  vq_fused<<<dim3(1024), dim3(1024), 0, stream>>>(ze, cbk, u, out);
}